// Round 1
// baseline (1884.252 us; speedup 1.0000x reference)
//
#include <hip/hip_runtime.h>
#include <cmath>

#define N_NODES 50000
#define N_EDGES 800000

// ---------------------------------------------------------------------------
// K1: feat = h @ W_gat (N,128); el[n,h] = <feat[n,h,:],attn_l[h,:]>; er likewise
// Block = 128 threads, thread t owns output column t. W_gat (16 KB) in LDS.
// ---------------------------------------------------------------------------
__global__ __launch_bounds__(128) void k_feat(
        const float* __restrict__ h, const float* __restrict__ Wg,
        const float* __restrict__ attn_l, const float* __restrict__ attn_r,
        float* __restrict__ feat, float* __restrict__ el, float* __restrict__ er) {
    __shared__ float Wl[32 * 128];
    __shared__ float hl[32];
    const int t = threadIdx.x;
    for (int i = t; i < 32 * 128; i += 128) Wl[i] = Wg[i];
    // attn_l is (H,F) row-major = 128 floats; index t == head*32+f
    const float al = attn_l[t];
    const float ar = attn_r[t];
    for (int n = blockIdx.x; n < N_NODES; n += gridDim.x) {
        if (t < 8) ((float4*)hl)[t] = ((const float4*)(h + (size_t)n * 32))[t];
        __syncthreads();
        float acc = 0.f;
#pragma unroll
        for (int k = 0; k < 32; ++k) acc = fmaf(hl[k], Wl[k * 128 + t], acc);
        feat[(size_t)n * 128 + t] = acc;
        float pl = acc * al, pr = acc * ar;
#pragma unroll
        for (int m = 16; m >= 1; m >>= 1) {   // reduce within 32-lane head group
            pl += __shfl_xor(pl, m, 64);
            pr += __shfl_xor(pr, m, 64);
        }
        if ((t & 31) == 0) {
            el[n * 4 + (t >> 5)] = pl;
            er[n * 4 + (t >> 5)] = pr;
        }
        __syncthreads();
    }
}

// ---------------------------------------------------------------------------
// K2: single edge pass. 32 lanes per edge; lane j owns floats [4j,4j+4) of the
// 128-wide message (head = j>>3). Unnormalized accumulation:
//   agg[dst] += exp(leaky(el[src]+er[dst])) * feat[src];  denom[dst] += exp(...)
// (softmax max-shift dropped: mathematically identity, logits are O(1))
// ---------------------------------------------------------------------------
__global__ __launch_bounds__(256) void k_edge(
        const int* __restrict__ src, const int* __restrict__ dst,
        const float* __restrict__ feat,
        const float* __restrict__ el, const float* __restrict__ er,
        float* __restrict__ agg, float* __restrict__ denom) {
    const long long gid = (long long)blockIdx.x * 256 + threadIdx.x;
    const int e = (int)(gid >> 5);
    if (e >= N_EDGES) return;
    const int j = threadIdx.x & 31;
    const int s = src[e];
    const int d = dst[e];
    const float4 l4 = ((const float4*)el)[s];
    const float4 r4 = ((const float4*)er)[d];
    const float lv[4] = {l4.x, l4.y, l4.z, l4.w};
    const float rv[4] = {r4.x, r4.y, r4.z, r4.w};
    const int head = j >> 3;
    float ev = lv[head] + rv[head];
    ev = ev > 0.f ? ev : 0.2f * ev;           // leaky_relu(0.2)
    const float ee = expf(ev);
    const float4 fv = ((const float4*)feat)[(size_t)s * 32 + j];
    float* ap = agg + (size_t)d * 128 + 4 * j;
    unsafeAtomicAdd(ap + 0, fv.x * ee);
    unsafeAtomicAdd(ap + 1, fv.y * ee);
    unsafeAtomicAdd(ap + 2, fv.z * ee);
    unsafeAtomicAdd(ap + 3, fv.w * ee);
    if ((j & 7) == 0) unsafeAtomicAdd(denom + (size_t)d * 4 + head, ee);
}

// ---------------------------------------------------------------------------
// K3: x = agg/denom (0 if no in-edges); GRU gates; out = elu(h_new)
// Block = 128 threads, one node per iteration; weights transposed in LDS
// (Wt[k*96+r] -> bank r%32, 2-way across a wave = conflict-free).
// ---------------------------------------------------------------------------
__global__ __launch_bounds__(128) void k_gru(
        const float* __restrict__ agg, const float* __restrict__ denom,
        const float* __restrict__ h,
        const float* __restrict__ W_ih, const float* __restrict__ W_hh,
        const float* __restrict__ b_ih, const float* __restrict__ b_hh,
        float* __restrict__ out) {
    __shared__ float Wi[128 * 96];   // transposed [k][r]
    __shared__ float Wh[32 * 96];    // transposed [k][r]
    __shared__ float xl[128], hl[32], gi[96], gh[96];
    const int t = threadIdx.x;
    for (int i = t; i < 96 * 128; i += 128) {
        const int r = i >> 7, k = i & 127;
        Wi[k * 96 + r] = W_ih[i];
    }
    for (int i = t; i < 96 * 32; i += 128) {
        const int r = i >> 5, k = i & 31;
        Wh[k * 96 + r] = W_hh[i];
    }
    const float bi = t < 96 ? b_ih[t] : 0.f;
    const float bh = t < 96 ? b_hh[t] : 0.f;
    for (int n = blockIdx.x; n < N_NODES; n += gridDim.x) {
        {
            const float dn = denom[(size_t)n * 4 + (t >> 5)];
            const float v = agg[(size_t)n * 128 + t];
            xl[t] = dn > 0.f ? v / dn : 0.f;
        }
        if (t < 32) hl[t] = h[(size_t)n * 32 + t];
        __syncthreads();
        if (t < 96) {
            float ai = bi, ah = bh;
#pragma unroll 4
            for (int k = 0; k < 128; ++k) ai = fmaf(xl[k], Wi[k * 96 + t], ai);
#pragma unroll 4
            for (int k = 0; k < 32; ++k) ah = fmaf(hl[k], Wh[k * 96 + t], ah);
            gi[t] = ai;
            gh[t] = ah;
        }
        __syncthreads();
        if (t < 32) {
            const float rr = 1.f / (1.f + expf(-(gi[t] + gh[t])));
            const float zz = 1.f / (1.f + expf(-(gi[32 + t] + gh[32 + t])));
            const float nn = tanhf(gi[64 + t] + rr * gh[64 + t]);
            const float hn = (1.f - zz) * nn + zz * hl[t];
            out[(size_t)n * 32 + t] = hn > 0.f ? hn : expm1f(hn);
        }
        __syncthreads();
    }
}

extern "C" void kernel_launch(void* const* d_in, const int* in_sizes, int n_in,
                              void* d_out, int out_size, void* d_ws, size_t ws_size,
                              hipStream_t stream) {
    const float* h   = (const float*)d_in[0];
    const float* Wg  = (const float*)d_in[1];
    const float* al  = (const float*)d_in[2];
    const float* ar  = (const float*)d_in[3];
    const float* Wih = (const float*)d_in[4];
    const float* Whh = (const float*)d_in[5];
    const float* bih = (const float*)d_in[6];
    const float* bhh = (const float*)d_in[7];
    const int* src   = (const int*)d_in[8];
    const int* dst   = (const int*)d_in[9];
    float* out = (float*)d_out;

    float* ws    = (float*)d_ws;
    float* agg   = ws;                              // N*128
    float* denom = agg + (size_t)N_NODES * 128;     // N*4
    float* feat  = denom + (size_t)N_NODES * 4;     // N*128
    float* el    = feat + (size_t)N_NODES * 128;    // N*4
    float* er    = el + (size_t)N_NODES * 4;        // N*4

    // zero agg+denom (contiguous) — ws is poisoned 0xAA before every launch
    hipMemsetAsync(agg, 0, (size_t)N_NODES * 132 * sizeof(float), stream);

    k_feat<<<512, 128, 0, stream>>>(h, Wg, al, ar, feat, el, er);

    const int eblocks = (N_EDGES * 32 + 255) / 256;   // 100000
    k_edge<<<eblocks, 256, 0, stream>>>(src, dst, feat, el, er, agg, denom);

    k_gru<<<512, 128, 0, stream>>>(agg, denom, h, Wih, Whh, bih, bhh, out);
}

// Round 3
// 461.986 us; speedup vs baseline: 4.0786x; 4.0786x over previous
//
#include <hip/hip_runtime.h>
#include <cmath>

#define N_NODES 50000
#define N_EDGES 800000

// ---------------------------------------------------------------------------
// K1: feat = h @ W_gat (N,128); el/er per-head dots. 4 nodes per iteration:
// each Wl LDS read feeds 4 FMAs; thread t owns output column t.
// ---------------------------------------------------------------------------
__global__ __launch_bounds__(128) void k_feat(
        const float* __restrict__ h, const float* __restrict__ Wg,
        const float* __restrict__ attn_l, const float* __restrict__ attn_r,
        float* __restrict__ feat, float* __restrict__ el, float* __restrict__ er) {
    __shared__ float Wl[32 * 128];
    __shared__ float hl[4][32];
    const int t = threadIdx.x;
    for (int i = t; i < 32 * 128; i += 128) Wl[i] = Wg[i];
    const float al = attn_l[t];   // (H,F) row-major: t = head*32+f
    const float ar = attn_r[t];
    const int head = t >> 5;
    // N_NODES % 4 == 0, so every group of 4 is full
    for (int base = blockIdx.x * 4; base < N_NODES; base += gridDim.x * 4) {
        hl[t >> 5][t & 31] = h[(size_t)(base + (t >> 5)) * 32 + (t & 31)];
        __syncthreads();
        float a0 = 0.f, a1 = 0.f, a2 = 0.f, a3 = 0.f;
#pragma unroll
        for (int k = 0; k < 32; ++k) {
            const float w = Wl[k * 128 + t];
            a0 = fmaf(hl[0][k], w, a0);
            a1 = fmaf(hl[1][k], w, a1);
            a2 = fmaf(hl[2][k], w, a2);
            a3 = fmaf(hl[3][k], w, a3);
        }
        float acc[4] = {a0, a1, a2, a3};
#pragma unroll
        for (int u = 0; u < 4; ++u) {
            feat[(size_t)(base + u) * 128 + t] = acc[u];
            float pl = acc[u] * al, pr = acc[u] * ar;
#pragma unroll
            for (int m = 16; m >= 1; m >>= 1) {
                pl += __shfl_xor(pl, m, 64);
                pr += __shfl_xor(pr, m, 64);
            }
            if ((t & 31) == 0) {
                el[(base + u) * 4 + head] = pl;
                er[(base + u) * 4 + head] = pr;
            }
        }
        __syncthreads();
    }
}

// ---------------------------------------------------------------------------
// K2a: in-degree histogram (counts zeroed by memsetAsync beforehand)
// ---------------------------------------------------------------------------
__global__ __launch_bounds__(256) void k_hist(
        const int* __restrict__ dst, int* __restrict__ counts) {
    const int e = blockIdx.x * 256 + threadIdx.x;
    if (e < N_EDGES) atomicAdd(&counts[dst[e]], 1);
}

// ---------------------------------------------------------------------------
// K2b: exclusive scan of counts -> offsets[N+1]; also rewrites counts with the
// exclusive offsets (reused as scatter cursors). Single block, 1024 threads.
// ---------------------------------------------------------------------------
__global__ __launch_bounds__(1024) void k_scan(
        int* __restrict__ counts, int* __restrict__ offsets) {
    __shared__ int wbase[16];
    __shared__ int carry_s;
    const int t = threadIdx.x;
    const int wave = t >> 6, lane = t & 63;
    if (t == 0) carry_s = 0;
    __syncthreads();
    for (int base = 0; base < N_NODES; base += 1024) {
        const int idx = base + t;
        const int v = (idx < N_NODES) ? counts[idx] : 0;
        int x = v;
#pragma unroll
        for (int m = 1; m < 64; m <<= 1) {
            const int y = __shfl_up(x, m, 64);
            if (lane >= m) x += y;
        }
        if (lane == 63) wbase[wave] = x;      // wave total (inclusive)
        __syncthreads();
        if (t == 0) {
            int s = carry_s;
#pragma unroll
            for (int i = 0; i < 16; ++i) { const int tmp = wbase[i]; wbase[i] = s; s += tmp; }
            carry_s = s;
        }
        __syncthreads();
        if (idx < N_NODES) {
            const int off = wbase[wave] + x - v;   // exclusive
            offsets[idx] = off;
            counts[idx]  = off;                    // cursor copy
        }
        __syncthreads();                           // wbase reuse next iter
    }
    if (t == 0) offsets[N_NODES] = carry_s;        // == N_EDGES
}

// ---------------------------------------------------------------------------
// K2c: scatter src ids into dst-sorted order (cursor = counts)
// ---------------------------------------------------------------------------
__global__ __launch_bounds__(256) void k_scatter(
        const int* __restrict__ src, const int* __restrict__ dst,
        int* __restrict__ cursor, int* __restrict__ srcs) {
    const int e = blockIdx.x * 256 + threadIdx.x;
    if (e < N_EDGES) {
        const int pos = atomicAdd(&cursor[dst[e]], 1);
        srcs[pos] = src[e];
    }
}

// ---------------------------------------------------------------------------
// K3: gather-aggregate. One 128-thread block per dst node; thread t owns
// column t. Per 128-edge chunk: stage src ids + softmax numerators ee in LDS,
// then the inner loop is 1 coalesced feat dword + 2 LDS reads + 1 FMA / edge.
// No float atomics anywhere. x = acc/denom written normalized.
// ---------------------------------------------------------------------------
__global__ __launch_bounds__(128) void k_aggr(
        const int* __restrict__ offsets, const int* __restrict__ srcs,
        const float* __restrict__ feat,
        const float* __restrict__ el, const float* __restrict__ er,
        float* __restrict__ x) {
    const int n = blockIdx.x;
    const int t = threadIdx.x;
    const int head = t >> 5;
    __shared__ int   sl[128];
    __shared__ float eel[128 * 4];
    __shared__ float ern[4];
    __shared__ float dsum_s[4];
    if (t < 4) { ern[t] = er[n * 4 + t]; dsum_s[t] = 0.f; }
    const int start = offsets[n], end = offsets[n + 1];
    float acc = 0.f;
    float psum = 0.f;                       // per-thread denom partial, head = t&3
    for (int chunk = start; chunk < end; chunk += 128) {
        const int cnt = min(128, end - chunk);
        if (t < cnt) sl[t] = srcs[chunk + t];
        __syncthreads();
        for (int j = t; j < cnt * 4; j += 128) {   // j&3 == t&3 always
            const int s = sl[j >> 2];
            float v = el[(size_t)s * 4 + (j & 3)] + ern[j & 3];
            v = v > 0.f ? v : 0.2f * v;
            const float e = expf(v);
            eel[j] = e;
            psum += e;
        }
        __syncthreads();
#pragma unroll 4
        for (int i = 0; i < cnt; ++i) {
            acc = fmaf(eel[i * 4 + head], feat[(size_t)sl[i] * 128 + t], acc);
        }
        __syncthreads();                    // sl/eel reuse next chunk
    }
    atomicAdd(&dsum_s[t & 3], psum);        // LDS atomic, once per thread
    __syncthreads();
    const float dn = dsum_s[head];
    x[(size_t)n * 128 + t] = (end > start) ? acc / dn : 0.f;
}

// ---------------------------------------------------------------------------
// K4: GRU + elu. 4 nodes per iteration; each Wi/Wh LDS read feeds 4 FMAs.
// ---------------------------------------------------------------------------
__global__ __launch_bounds__(128) void k_gru(
        const float* __restrict__ x, const float* __restrict__ h,
        const float* __restrict__ W_ih, const float* __restrict__ W_hh,
        const float* __restrict__ b_ih, const float* __restrict__ b_hh,
        float* __restrict__ out) {
    __shared__ float Wi[128 * 96];   // transposed [k][r]
    __shared__ float Wh[32 * 96];    // transposed [k][r]
    __shared__ float xl[4][128], hl[4][32], gi[4][96], gh[4][96];
    const int t = threadIdx.x;
    for (int i = t; i < 96 * 128; i += 128) {
        Wi[(i & 127) * 96 + (i >> 7)] = W_ih[i];
    }
    for (int i = t; i < 96 * 32; i += 128) {
        Wh[(i & 31) * 96 + (i >> 5)] = W_hh[i];
    }
    const float bi = t < 96 ? b_ih[t] : 0.f;
    const float bh = t < 96 ? b_hh[t] : 0.f;
    for (int base = blockIdx.x * 4; base < N_NODES; base += gridDim.x * 4) {
#pragma unroll
        for (int u = 0; u < 4; ++u) xl[u][t] = x[(size_t)(base + u) * 128 + t];
        hl[t >> 5][t & 31] = h[(size_t)(base + (t >> 5)) * 32 + (t & 31)];
        __syncthreads();
        if (t < 96) {
            float ai0 = bi, ai1 = bi, ai2 = bi, ai3 = bi;
            float ah0 = bh, ah1 = bh, ah2 = bh, ah3 = bh;
#pragma unroll 4
            for (int k = 0; k < 128; ++k) {
                const float w = Wi[k * 96 + t];
                ai0 = fmaf(xl[0][k], w, ai0);
                ai1 = fmaf(xl[1][k], w, ai1);
                ai2 = fmaf(xl[2][k], w, ai2);
                ai3 = fmaf(xl[3][k], w, ai3);
            }
#pragma unroll 4
            for (int k = 0; k < 32; ++k) {
                const float w = Wh[k * 96 + t];
                ah0 = fmaf(hl[0][k], w, ah0);
                ah1 = fmaf(hl[1][k], w, ah1);
                ah2 = fmaf(hl[2][k], w, ah2);
                ah3 = fmaf(hl[3][k], w, ah3);
            }
            gi[0][t] = ai0; gi[1][t] = ai1; gi[2][t] = ai2; gi[3][t] = ai3;
            gh[0][t] = ah0; gh[1][t] = ah1; gh[2][t] = ah2; gh[3][t] = ah3;
        }
        __syncthreads();
        {
            const int u = t >> 5, c = t & 31;
            const float rr = 1.f / (1.f + expf(-(gi[u][c] + gh[u][c])));
            const float zz = 1.f / (1.f + expf(-(gi[u][32 + c] + gh[u][32 + c])));
            const float nn = tanhf(gi[u][64 + c] + rr * gh[u][64 + c]);
            const float hn = (1.f - zz) * nn + zz * hl[u][c];
            out[(size_t)(base + u) * 32 + c] = hn > 0.f ? hn : expm1f(hn);
        }
        __syncthreads();
    }
}

extern "C" void kernel_launch(void* const* d_in, const int* in_sizes, int n_in,
                              void* d_out, int out_size, void* d_ws, size_t ws_size,
                              hipStream_t stream) {
    const float* h   = (const float*)d_in[0];
    const float* Wg  = (const float*)d_in[1];
    const float* al  = (const float*)d_in[2];
    const float* ar  = (const float*)d_in[3];
    const float* Wih = (const float*)d_in[4];
    const float* Whh = (const float*)d_in[5];
    const float* bih = (const float*)d_in[6];
    const float* bhh = (const float*)d_in[7];
    const int* src   = (const int*)d_in[8];
    const int* dst   = (const int*)d_in[9];
    float* out = (float*)d_out;

    // workspace layout (~56.4 MB)
    float* ws   = (float*)d_ws;
    float* feat = ws;                                   // N*128
    float* el   = feat + (size_t)N_NODES * 128;         // N*4
    float* er   = el + (size_t)N_NODES * 4;             // N*4
    float* x    = er + (size_t)N_NODES * 4;             // N*128
    int* counts  = (int*)(x + (size_t)N_NODES * 128);   // N (histogram -> cursor)
    int* offsets = counts + N_NODES;                    // N+1
    int* srcs    = offsets + N_NODES + 1;               // E

    hipMemsetAsync(counts, 0, N_NODES * sizeof(int), stream);

    k_feat<<<512, 128, 0, stream>>>(h, Wg, al, ar, feat, el, er);
    k_hist<<<(N_EDGES + 255) / 256, 256, 0, stream>>>(dst, counts);
    k_scan<<<1, 1024, 0, stream>>>(counts, offsets);
    k_scatter<<<(N_EDGES + 255) / 256, 256, 0, stream>>>(src, dst, counts, srcs);
    k_aggr<<<N_NODES, 128, 0, stream>>>(offsets, srcs, feat, el, er, x);
    k_gru<<<512, 128, 0, stream>>>(x, h, Wih, Whh, bih, bhh, out);
}

// Round 4
// 299.000 us; speedup vs baseline: 6.3018x; 1.5451x over previous
//
#include <hip/hip_runtime.h>
#include <hip/hip_bf16.h>
#include <cmath>

#define N_NODES 50000
#define N_EDGES 800000

typedef __attribute__((ext_vector_type(8))) short bf16x8;
typedef __attribute__((ext_vector_type(4))) float f32x4;

// ---------------------------------------------------------------------------
// K1: feat = h @ W_gat (N,128); el/er per-head dots. 4 nodes per iteration.
// ---------------------------------------------------------------------------
__global__ __launch_bounds__(128) void k_feat(
        const float* __restrict__ h, const float* __restrict__ Wg,
        const float* __restrict__ attn_l, const float* __restrict__ attn_r,
        float* __restrict__ feat, float* __restrict__ el, float* __restrict__ er) {
    __shared__ float Wl[32 * 128];
    __shared__ float hl[4][32];
    const int t = threadIdx.x;
    for (int i = t; i < 32 * 128; i += 128) Wl[i] = Wg[i];
    const float al = attn_l[t];   // (H,F) row-major: t = head*32+f
    const float ar = attn_r[t];
    const int head = t >> 5;
    for (int base = blockIdx.x * 4; base < N_NODES; base += gridDim.x * 4) {
        hl[t >> 5][t & 31] = h[(size_t)(base + (t >> 5)) * 32 + (t & 31)];
        __syncthreads();
        float a0 = 0.f, a1 = 0.f, a2 = 0.f, a3 = 0.f;
#pragma unroll
        for (int k = 0; k < 32; ++k) {
            const float w = Wl[k * 128 + t];
            a0 = fmaf(hl[0][k], w, a0);
            a1 = fmaf(hl[1][k], w, a1);
            a2 = fmaf(hl[2][k], w, a2);
            a3 = fmaf(hl[3][k], w, a3);
        }
        float acc[4] = {a0, a1, a2, a3};
#pragma unroll
        for (int u = 0; u < 4; ++u) {
            feat[(size_t)(base + u) * 128 + t] = acc[u];
            float pl = acc[u] * al, pr = acc[u] * ar;
#pragma unroll
            for (int m = 16; m >= 1; m >>= 1) {
                pl += __shfl_xor(pl, m, 64);
                pr += __shfl_xor(pr, m, 64);
            }
            if ((t & 31) == 0) {
                el[(base + u) * 4 + head] = pl;
                er[(base + u) * 4 + head] = pr;
            }
        }
        __syncthreads();
    }
}

// ---------------------------------------------------------------------------
// K2a: in-degree histogram
// ---------------------------------------------------------------------------
__global__ __launch_bounds__(256) void k_hist(
        const int* __restrict__ dst, int* __restrict__ counts) {
    const int e = blockIdx.x * 256 + threadIdx.x;
    if (e < N_EDGES) atomicAdd(&counts[dst[e]], 1);
}

// ---------------------------------------------------------------------------
// K2b: hierarchical scan, pass 1 — per-1024-chunk exclusive scan + chunk sums
// ---------------------------------------------------------------------------
__global__ __launch_bounds__(1024) void k_scanA(
        const int* __restrict__ counts, int* __restrict__ offsets,
        int* __restrict__ bsums) {
    __shared__ int wtot[16];
    const int t = threadIdx.x;
    const int wave = t >> 6, lane = t & 63;
    const int idx = blockIdx.x * 1024 + t;
    const int v = (idx < N_NODES) ? counts[idx] : 0;
    int x = v;
#pragma unroll
    for (int m = 1; m < 64; m <<= 1) {
        const int y = __shfl_up(x, m, 64);
        if (lane >= m) x += y;
    }
    if (lane == 63) wtot[wave] = x;
    __syncthreads();
    if (t == 0) {
        int s = 0;
#pragma unroll
        for (int i = 0; i < 16; ++i) { const int tmp = wtot[i]; wtot[i] = s; s += tmp; }
        bsums[blockIdx.x] = s;
    }
    __syncthreads();
    if (idx < N_NODES) offsets[idx] = wtot[wave] + x - v;
}

// K2c: scan 49 chunk sums in place (exclusive); also set offsets[N]=E
__global__ __launch_bounds__(64) void k_scanB(
        int* __restrict__ bsums, int* __restrict__ offsets, int nblocks) {
    if (threadIdx.x == 0) {
        int s = 0;
        for (int i = 0; i < nblocks; ++i) { const int v = bsums[i]; bsums[i] = s; s += v; }
        offsets[N_NODES] = N_EDGES;
    }
}

// K2d: add chunk base; duplicate into cursor array
__global__ __launch_bounds__(1024) void k_scanC(
        int* __restrict__ offsets, const int* __restrict__ bsums,
        int* __restrict__ cursor) {
    const int idx = blockIdx.x * 1024 + threadIdx.x;
    if (idx < N_NODES) {
        const int off = offsets[idx] + bsums[blockIdx.x];
        offsets[idx] = off;
        cursor[idx] = off;
    }
}

// ---------------------------------------------------------------------------
// K2e: scatter src ids into dst-sorted order
// ---------------------------------------------------------------------------
__global__ __launch_bounds__(256) void k_scatter(
        const int* __restrict__ src, const int* __restrict__ dst,
        int* __restrict__ cursor, int* __restrict__ srcs) {
    const int e = blockIdx.x * 256 + threadIdx.x;
    if (e < N_EDGES) {
        const int pos = atomicAdd(&cursor[dst[e]], 1);
        srcs[pos] = src[e];
    }
}

// ---------------------------------------------------------------------------
// K_prepw: Wc[192][160] bf16, block-diagonal [W_ih | 0; 0 | W_hh]
// ---------------------------------------------------------------------------
__global__ __launch_bounds__(256) void k_prepw(
        const float* __restrict__ Wih, const float* __restrict__ Whh,
        __hip_bfloat16* __restrict__ Wc) {
    const int idx = blockIdx.x * 256 + threadIdx.x;   // grid covers 192*160
    if (idx >= 192 * 160) return;
    const int r = idx / 160, k = idx - r * 160;
    float v = 0.f;
    if (r < 96) { if (k < 128) v = Wih[r * 128 + k]; }
    else        { if (k >= 128) v = Whh[(r - 96) * 32 + (k - 128)]; }
    Wc[idx] = __float2bfloat16(v);
}

// ---------------------------------------------------------------------------
// K3: gather-aggregate, wave-per-node (barrier-free). Lane owns cols 2l,2l+1
// (one wave reads a full 512B feat row, perfectly coalesced). Writes the
// GRU GEMM input xh[n] = [bf16(x[n][0..128]) | bf16(h[n][0..32])].
// ---------------------------------------------------------------------------
__global__ __launch_bounds__(256) void k_aggr(
        const int* __restrict__ offsets, const int* __restrict__ srcs,
        const float* __restrict__ feat,
        const float* __restrict__ el, const float* __restrict__ er,
        const float* __restrict__ h, __hip_bfloat16* __restrict__ xh) {
    const int wave = threadIdx.x >> 6;
    const int lane = threadIdx.x & 63;
    const int n = blockIdx.x * 4 + wave;
    if (n >= N_NODES) return;
    __shared__ int   sl_s[4][64];
    __shared__ float eel_s[4][256];
    int*   sl  = sl_s[wave];
    float* eel = eel_s[wave];
    const int hs = lane & 3;          // head this lane computes softmax terms for
    const int hc = lane >> 4;         // head of this lane's feat columns
    const float ern = er[n * 4 + hs];
    const int start = offsets[n], end = offsets[n + 1];
    float ax = 0.f, ay = 0.f;
    float psum = 0.f;
    for (int chunk = start; chunk < end; chunk += 64) {
        const int cnt = min(64, end - chunk);
        if (lane < cnt) sl[lane] = srcs[chunk + lane];
        __builtin_amdgcn_wave_barrier();
#pragma unroll
        for (int p = 0; p < 4; ++p) {
            const int j = p * 64 + lane;           // j&3 == lane&3
            if (j < cnt * 4) {
                const int s = sl[j >> 2];
                float v = el[(size_t)s * 4 + hs] + ern;
                v = v > 0.f ? v : 0.2f * v;        // leaky_relu(0.2)
                const float e = expf(v);
                eel[j] = e;
                psum += e;
            }
        }
        __builtin_amdgcn_wave_barrier();
        for (int i = 0; i < cnt; ++i) {
            const int s = sl[i];
            const float2 f = ((const float2*)(feat + (size_t)s * 128))[lane];
            const float w = eel[i * 4 + hc];
            ax = fmaf(w, f.x, ax);
            ay = fmaf(w, f.y, ay);
        }
        __builtin_amdgcn_wave_barrier();
    }
    // denom: sum psum over the 16 lanes sharing hs, then fetch head hc's total
#pragma unroll
    for (int m = 4; m < 64; m <<= 1) psum += __shfl_xor(psum, m, 64);
    const float dn = __shfl(psum, hc, 64);        // lane hc holds head hc's sum
    const float inv = (end > start) ? 1.f / dn : 0.f;
    __hip_bfloat16* xr = xh + (size_t)n * 160;
    __hip_bfloat162 v2;
    v2.x = __float2bfloat16(ax * inv);
    v2.y = __float2bfloat16(ay * inv);
    ((__hip_bfloat162*)xr)[lane] = v2;
    if (lane < 32) xr[128 + lane] = __float2bfloat16(h[(size_t)n * 32 + lane]);
}

// ---------------------------------------------------------------------------
// K4: GRU via bf16 MFMA. GEMM: [gi|gh](50000,192) = xh(50000,160) @ Wc^T.
// Wave handles one 16-row M-tile; block of 4 waves covers 64 nodes.
// Frag layouts (verified, §3): A/B elem j of lane l -> [idx=l&15][k=(l>>4)*8+j];
// C/D reg i of lane l -> col=l&15, row=(l>>4)*4+i.
// ---------------------------------------------------------------------------
__global__ __launch_bounds__(256) void k_gru_mfma(
        const __hip_bfloat16* __restrict__ xh, const __hip_bfloat16* __restrict__ Wc,
        const float* __restrict__ bih, const float* __restrict__ bhh,
        const float* __restrict__ h, float* __restrict__ out) {
    const int lane = threadIdx.x & 63;
    const int wave = threadIdx.x >> 6;
    const int li = lane & 15, quad = lane >> 4;
    const int m_base = blockIdx.x * 64 + wave * 16;
    const int arow = min(m_base + li, N_NODES - 1);
    const bf16x8* ap = (const bf16x8*)(xh + (size_t)arow * 160 + quad * 8);
    const bf16x8 a0 = ap[0], a1 = ap[4], a2 = ap[8], a3 = ap[12], a4 = ap[16];
    f32x4 acc[12];
#pragma unroll
    for (int j = 0; j < 12; ++j) acc[j] = (f32x4){0.f, 0.f, 0.f, 0.f};
#pragma unroll
    for (int j = 0; j < 12; ++j) {
        const bf16x8* bp = (const bf16x8*)(Wc + (size_t)(j * 16 + li) * 160 + quad * 8);
        acc[j] = __builtin_amdgcn_mfma_f32_16x16x32_bf16(a0, bp[0],  acc[j], 0, 0, 0);
        acc[j] = __builtin_amdgcn_mfma_f32_16x16x32_bf16(a1, bp[4],  acc[j], 0, 0, 0);
        acc[j] = __builtin_amdgcn_mfma_f32_16x16x32_bf16(a2, bp[8],  acc[j], 0, 0, 0);
        acc[j] = __builtin_amdgcn_mfma_f32_16x16x32_bf16(a3, bp[12], acc[j], 0, 0, 0);
        acc[j] = __builtin_amdgcn_mfma_f32_16x16x32_bf16(a4, bp[16], acc[j], 0, 0, 0);
    }
    // biases for this lane's 12 gate columns (g = jg*16 + li)
    const float bi0 = bih[li],      bh0 = bhh[li];
    const float bi1 = bih[16 + li], bh1 = bhh[16 + li];
    const float bi2 = bih[32 + li], bh2 = bhh[32 + li];
    const float bi3 = bih[48 + li], bh3 = bhh[48 + li];
    const float bi4 = bih[64 + li], bh4 = bhh[64 + li];
    const float bi5 = bih[80 + li], bh5 = bhh[80 + li];
#pragma unroll
    for (int i = 0; i < 4; ++i) {
        const int m = m_base + quad * 4 + i;
        if (m >= N_NODES) continue;
        // column c0 = li : r from jg0, z from jg2, n from jg4 (gh at +6)
        {
            const float rr = 1.f / (1.f + expf(-(acc[0][i] + bi0 + acc[6][i] + bh0)));
            const float zz = 1.f / (1.f + expf(-(acc[2][i] + bi2 + acc[8][i] + bh2)));
            const float nn = tanhf(acc[4][i] + bi4 + rr * (acc[10][i] + bh4));
            const float hv = h[(size_t)m * 32 + li];
            const float hn = (1.f - zz) * nn + zz * hv;
            out[(size_t)m * 32 + li] = hn > 0.f ? hn : expm1f(hn);
        }
        // column c1 = 16 + li : jg1 / jg3 / jg5
        {
            const float rr = 1.f / (1.f + expf(-(acc[1][i] + bi1 + acc[7][i] + bh1)));
            const float zz = 1.f / (1.f + expf(-(acc[3][i] + bi3 + acc[9][i] + bh3)));
            const float nn = tanhf(acc[5][i] + bi5 + rr * (acc[11][i] + bh5));
            const float hv = h[(size_t)m * 32 + 16 + li];
            const float hn = (1.f - zz) * nn + zz * hv;
            out[(size_t)m * 32 + 16 + li] = hn > 0.f ? hn : expm1f(hn);
        }
    }
}

extern "C" void kernel_launch(void* const* d_in, const int* in_sizes, int n_in,
                              void* d_out, int out_size, void* d_ws, size_t ws_size,
                              hipStream_t stream) {
    const float* h   = (const float*)d_in[0];
    const float* Wg  = (const float*)d_in[1];
    const float* al  = (const float*)d_in[2];
    const float* ar  = (const float*)d_in[3];
    const float* Wih = (const float*)d_in[4];
    const float* Whh = (const float*)d_in[5];
    const float* bih = (const float*)d_in[6];
    const float* bhh = (const float*)d_in[7];
    const int* src   = (const int*)d_in[8];
    const int* dst   = (const int*)d_in[9];
    float* out = (float*)d_out;

    // workspace layout (~47 MB)
    float* ws   = (float*)d_ws;
    float* feat = ws;                                        // N*128 f32
    float* el   = feat + (size_t)N_NODES * 128;              // N*4
    float* er   = el + (size_t)N_NODES * 4;                  // N*4
    __hip_bfloat16* xh = (__hip_bfloat16*)(er + (size_t)N_NODES * 4);  // 50048*160 bf16
    __hip_bfloat16* Wc = xh + (size_t)50048 * 160;           // 192*160 bf16
    int* counts  = (int*)(Wc + 192 * 160);                   // N
    int* offsets = counts + N_NODES;                         // N+1
    int* srcs    = offsets + N_NODES + 1;                    // E
    int* bsums   = srcs + N_EDGES;                           // 49

    hipMemsetAsync(counts, 0, N_NODES * sizeof(int), stream);

    k_prepw<<<(192 * 160 + 255) / 256, 256, 0, stream>>>(Wih, Whh, Wc);
    k_feat<<<512, 128, 0, stream>>>(h, Wg, al, ar, feat, el, er);
    k_hist<<<(N_EDGES + 255) / 256, 256, 0, stream>>>(dst, counts);
    const int nscan = (N_NODES + 1023) / 1024;               // 49
    k_scanA<<<nscan, 1024, 0, stream>>>(counts, offsets, bsums);
    k_scanB<<<1, 64, 0, stream>>>(bsums, offsets, nscan);
    k_scanC<<<nscan, 1024, 0, stream>>>(offsets, bsums, counts);
    k_scatter<<<(N_EDGES + 255) / 256, 256, 0, stream>>>(src, dst, counts, srcs);
    k_aggr<<<(N_NODES + 3) / 4, 256, 0, stream>>>(offsets, srcs, feat, el, er, h, xh);
    k_gru_mfma<<<(N_NODES + 63) / 64, 256, 0, stream>>>(xh, Wc, bih, bhh, h, out);
}

// Round 5
// 212.817 us; speedup vs baseline: 8.8538x; 1.4050x over previous
//
#include <hip/hip_runtime.h>
#include <hip/hip_bf16.h>
#include <cmath>

#define N_NODES 50000
#define N_EDGES 800000

typedef __attribute__((ext_vector_type(8))) short bf16x8;
typedef __attribute__((ext_vector_type(4))) float f32x4;

// ---------------------------------------------------------------------------
// k_prepx: h (f32) -> hb (bf16), 4 elems/thread
// ---------------------------------------------------------------------------
__global__ __launch_bounds__(256) void k_prepx(
        const float* __restrict__ h, __hip_bfloat16* __restrict__ hb) {
    const int i = blockIdx.x * 256 + threadIdx.x;   // i indexes groups of 4
    if (i >= N_NODES * 32 / 4) return;
    const float4 v = ((const float4*)h)[i];
    __hip_bfloat16* o = hb + (size_t)i * 4;
    o[0] = __float2bfloat16(v.x);
    o[1] = __float2bfloat16(v.y);
    o[2] = __float2bfloat16(v.z);
    o[3] = __float2bfloat16(v.w);
}

// ---------------------------------------------------------------------------
// k_prepw: Wc[192][160] bf16, block-diagonal [W_ih | 0; 0 | W_hh] (GRU GEMM B)
// ---------------------------------------------------------------------------
__global__ __launch_bounds__(256) void k_prepw(
        const float* __restrict__ Wih, const float* __restrict__ Whh,
        __hip_bfloat16* __restrict__ Wc) {
    const int idx = blockIdx.x * 256 + threadIdx.x;
    if (idx >= 192 * 160) return;
    const int r = idx / 160, k = idx - r * 160;
    float v = 0.f;
    if (r < 96) { if (k < 128) v = Wih[r * 128 + k]; }
    else        { if (k >= 128) v = Whh[(r - 96) * 32 + (k - 128)]; }
    Wc[idx] = __float2bfloat16(v);
}

// ---------------------------------------------------------------------------
// k_prepc: Wcomb[144][32] bf16 (GAT GEMM B): rows 0..127 = Wg^T (feat cols),
// 128..131 = effective attn_l cols, 132..135 = attn_r cols, 136..143 = 0.
// ---------------------------------------------------------------------------
__global__ __launch_bounds__(256) void k_prepc(
        const float* __restrict__ Wg, const float* __restrict__ al,
        const float* __restrict__ ar, __hip_bfloat16* __restrict__ Wcomb) {
    const int idx = blockIdx.x * 256 + threadIdx.x;
    if (idx >= 144 * 32) return;
    const int row = idx >> 5, k = idx & 31;
    float v = 0.f;
    if (row < 128) {
        v = Wg[k * 128 + row];
    } else if (row < 136) {
        const int hd = (row - 128) & 3;
        const float* a = (row < 132) ? (al + hd * 32) : (ar + hd * 32);
        const float* w = Wg + k * 128 + hd * 32;
#pragma unroll
        for (int f = 0; f < 32; ++f) v = fmaf(w[f], a[f], v);
    }
    Wcomb[idx] = __float2bfloat16(v);
}

// ---------------------------------------------------------------------------
// K1: GAT projection via MFMA. M=50000 (3125 16-row tiles), N=144, K=32.
// One wave per M-tile: 9 MFMAs. Tiles 0..7 -> feat (bf16); tile 8 -> el/er f32.
// A/B frag: [idx=lane&15][k=(lane>>4)*8+j]; C/D: col=lane&15, row=quad*4+reg.
// ---------------------------------------------------------------------------
__global__ __launch_bounds__(256) void k_feat_mfma(
        const __hip_bfloat16* __restrict__ hb, const __hip_bfloat16* __restrict__ Wcomb,
        __hip_bfloat16* __restrict__ feat, float* __restrict__ el, float* __restrict__ er) {
    const int lane = threadIdx.x & 63;
    const int wave = threadIdx.x >> 6;
    const int li = lane & 15, quad = lane >> 4;
    const int mt = blockIdx.x * 4 + wave;
    if (mt >= N_NODES / 16) return;            // 50000 = 16*3125 exactly
    const int m_base = mt * 16;
    const bf16x8 a = *(const bf16x8*)(hb + (size_t)(m_base + li) * 32 + quad * 8);
    f32x4 acc[9];
#pragma unroll
    for (int j = 0; j < 9; ++j) acc[j] = (f32x4){0.f, 0.f, 0.f, 0.f};
#pragma unroll
    for (int j = 0; j < 9; ++j) {
        const bf16x8 b = *(const bf16x8*)(Wcomb + (size_t)(j * 16 + li) * 32 + quad * 8);
        acc[j] = __builtin_amdgcn_mfma_f32_16x16x32_bf16(a, b, acc[j], 0, 0, 0);
    }
#pragma unroll
    for (int j = 0; j < 8; ++j) {
#pragma unroll
        for (int i = 0; i < 4; ++i) {
            const int m = m_base + quad * 4 + i;
            feat[(size_t)m * 128 + j * 16 + li] = __float2bfloat16(acc[j][i]);
        }
    }
    if (li < 8) {
#pragma unroll
        for (int i = 0; i < 4; ++i) {
            const int m = m_base + quad * 4 + i;
            if (li < 4) el[m * 4 + li] = acc[8][i];
            else        er[m * 4 + (li - 4)] = acc[8][i];
        }
    }
}

// ---------------------------------------------------------------------------
// K2a: in-degree histogram + per-edge rank within its dst segment
// ---------------------------------------------------------------------------
__global__ __launch_bounds__(256) void k_hist(
        const int* __restrict__ dst, int* __restrict__ counts,
        int* __restrict__ rank) {
    const int e = blockIdx.x * 256 + threadIdx.x;
    if (e < N_EDGES) rank[e] = atomicAdd(&counts[dst[e]], 1);
}

// ---------------------------------------------------------------------------
// K2b/c/d: hierarchical exclusive scan of counts -> offsets[N+1]
// ---------------------------------------------------------------------------
__global__ __launch_bounds__(1024) void k_scanA(
        const int* __restrict__ counts, int* __restrict__ offsets,
        int* __restrict__ bsums) {
    __shared__ int wtot[16];
    const int t = threadIdx.x;
    const int wave = t >> 6, lane = t & 63;
    const int idx = blockIdx.x * 1024 + t;
    const int v = (idx < N_NODES) ? counts[idx] : 0;
    int x = v;
#pragma unroll
    for (int m = 1; m < 64; m <<= 1) {
        const int y = __shfl_up(x, m, 64);
        if (lane >= m) x += y;
    }
    if (lane == 63) wtot[wave] = x;
    __syncthreads();
    if (t == 0) {
        int s = 0;
#pragma unroll
        for (int i = 0; i < 16; ++i) { const int tmp = wtot[i]; wtot[i] = s; s += tmp; }
        bsums[blockIdx.x] = s;
    }
    __syncthreads();
    if (idx < N_NODES) offsets[idx] = wtot[wave] + x - v;
}

__global__ __launch_bounds__(64) void k_scanB(
        int* __restrict__ bsums, int* __restrict__ offsets, int nblocks) {
    if (threadIdx.x == 0) {
        int s = 0;
        for (int i = 0; i < nblocks; ++i) { const int v = bsums[i]; bsums[i] = s; s += v; }
        offsets[N_NODES] = N_EDGES;
    }
}

__global__ __launch_bounds__(1024) void k_scanC(
        int* __restrict__ offsets, const int* __restrict__ bsums) {
    const int idx = blockIdx.x * 1024 + threadIdx.x;
    if (idx < N_NODES) offsets[idx] += bsums[blockIdx.x];
}

// ---------------------------------------------------------------------------
// K2e: scatter src ids into dst-sorted order — atomic-free (offsets + rank)
// ---------------------------------------------------------------------------
__global__ __launch_bounds__(256) void k_scatter(
        const int* __restrict__ src, const int* __restrict__ dst,
        const int* __restrict__ offsets, const int* __restrict__ rank,
        int* __restrict__ srcs) {
    const int e = blockIdx.x * 256 + threadIdx.x;
    if (e < N_EDGES) srcs[offsets[dst[e]] + rank[e]] = src[e];
}

// ---------------------------------------------------------------------------
// K3: gather-aggregate, wave-per-node, barrier-free. Lane owns cols 2l,2l+1
// as one bf16x2 (4 B): a wave reads a full 256 B bf16 feat row coalesced.
// Writes xh[n] = [bf16(x) | bf16(h)] for the GRU GEMM.
// ---------------------------------------------------------------------------
__global__ __launch_bounds__(256) void k_aggr(
        const int* __restrict__ offsets, const int* __restrict__ srcs,
        const __hip_bfloat16* __restrict__ feat,
        const float* __restrict__ el, const float* __restrict__ er,
        const float* __restrict__ h, __hip_bfloat16* __restrict__ xh) {
    const int wave = threadIdx.x >> 6;
    const int lane = threadIdx.x & 63;
    const int n = blockIdx.x * 4 + wave;
    if (n >= N_NODES) return;
    __shared__ int   sl_s[4][64];
    __shared__ float eel_s[4][256];
    int*   sl  = sl_s[wave];
    float* eel = eel_s[wave];
    const int hs = lane & 3;          // head this lane computes softmax terms for
    const int hc = lane >> 4;         // head of this lane's feat columns
    const float ern = er[n * 4 + hs];
    const int start = offsets[n], end = offsets[n + 1];
    float ax = 0.f, ay = 0.f;
    float psum = 0.f;
    for (int chunk = start; chunk < end; chunk += 64) {
        const int cnt = min(64, end - chunk);
        if (lane < cnt) sl[lane] = srcs[chunk + lane];
        __builtin_amdgcn_wave_barrier();
#pragma unroll
        for (int p = 0; p < 4; ++p) {
            const int j = p * 64 + lane;           // j&3 == lane&3
            if (j < cnt * 4) {
                const int s = sl[j >> 2];
                float v = el[(size_t)s * 4 + hs] + ern;
                v = v > 0.f ? v : 0.2f * v;        // leaky_relu(0.2)
                const float e = expf(v);
                eel[j] = e;
                psum += e;
            }
        }
        __builtin_amdgcn_wave_barrier();
        for (int i = 0; i < cnt; ++i) {
            const int s = sl[i];
            const __hip_bfloat162 f2 = ((const __hip_bfloat162*)(feat + (size_t)s * 128))[lane];
            const float w = eel[i * 4 + hc];
            ax = fmaf(w, __bfloat162float(f2.x), ax);
            ay = fmaf(w, __bfloat162float(f2.y), ay);
        }
        __builtin_amdgcn_wave_barrier();
    }
#pragma unroll
    for (int m = 4; m < 64; m <<= 1) psum += __shfl_xor(psum, m, 64);
    const float dn = __shfl(psum, hc, 64);        // lane hc holds head hc's sum
    const float inv = (end > start) ? 1.f / dn : 0.f;
    __hip_bfloat16* xr = xh + (size_t)n * 160;
    __hip_bfloat162 v2;
    v2.x = __float2bfloat16(ax * inv);
    v2.y = __float2bfloat16(ay * inv);
    ((__hip_bfloat162*)xr)[lane] = v2;
    if (lane < 32) xr[128 + lane] = __float2bfloat16(h[(size_t)n * 32 + lane]);
}

// ---------------------------------------------------------------------------
// K4: GRU via bf16 MFMA. [gi|gh](50000,192) = xh(50000,160) @ Wc^T.
// ---------------------------------------------------------------------------
__global__ __launch_bounds__(256) void k_gru_mfma(
        const __hip_bfloat16* __restrict__ xh, const __hip_bfloat16* __restrict__ Wc,
        const float* __restrict__ bih, const float* __restrict__ bhh,
        const float* __restrict__ h, float* __restrict__ out) {
    const int lane = threadIdx.x & 63;
    const int wave = threadIdx.x >> 6;
    const int li = lane & 15, quad = lane >> 4;
    const int m_base = blockIdx.x * 64 + wave * 16;
    const int arow = min(m_base + li, N_NODES - 1);
    const bf16x8* ap = (const bf16x8*)(xh + (size_t)arow * 160 + quad * 8);
    const bf16x8 a0 = ap[0], a1 = ap[4], a2 = ap[8], a3 = ap[12], a4 = ap[16];
    f32x4 acc[12];
#pragma unroll
    for (int j = 0; j < 12; ++j) acc[j] = (f32x4){0.f, 0.f, 0.f, 0.f};
#pragma unroll
    for (int j = 0; j < 12; ++j) {
        const bf16x8* bp = (const bf16x8*)(Wc + (size_t)(j * 16 + li) * 160 + quad * 8);
        acc[j] = __builtin_amdgcn_mfma_f32_16x16x32_bf16(a0, bp[0],  acc[j], 0, 0, 0);
        acc[j] = __builtin_amdgcn_mfma_f32_16x16x32_bf16(a1, bp[4],  acc[j], 0, 0, 0);
        acc[j] = __builtin_amdgcn_mfma_f32_16x16x32_bf16(a2, bp[8],  acc[j], 0, 0, 0);
        acc[j] = __builtin_amdgcn_mfma_f32_16x16x32_bf16(a3, bp[12], acc[j], 0, 0, 0);
        acc[j] = __builtin_amdgcn_mfma_f32_16x16x32_bf16(a4, bp[16], acc[j], 0, 0, 0);
    }
    const float bi0 = bih[li],      bh0 = bhh[li];
    const float bi1 = bih[16 + li], bh1 = bhh[16 + li];
    const float bi2 = bih[32 + li], bh2 = bhh[32 + li];
    const float bi3 = bih[48 + li], bh3 = bhh[48 + li];
    const float bi4 = bih[64 + li], bh4 = bhh[64 + li];
    const float bi5 = bih[80 + li], bh5 = bhh[80 + li];
#pragma unroll
    for (int i = 0; i < 4; ++i) {
        const int m = m_base + quad * 4 + i;
        if (m >= N_NODES) continue;
        {
            const float rr = 1.f / (1.f + expf(-(acc[0][i] + bi0 + acc[6][i] + bh0)));
            const float zz = 1.f / (1.f + expf(-(acc[2][i] + bi2 + acc[8][i] + bh2)));
            const float nn = tanhf(acc[4][i] + bi4 + rr * (acc[10][i] + bh4));
            const float hv = h[(size_t)m * 32 + li];
            const float hn = (1.f - zz) * nn + zz * hv;
            out[(size_t)m * 32 + li] = hn > 0.f ? hn : expm1f(hn);
        }
        {
            const float rr = 1.f / (1.f + expf(-(acc[1][i] + bi1 + acc[7][i] + bh1)));
            const float zz = 1.f / (1.f + expf(-(acc[3][i] + bi3 + acc[9][i] + bh3)));
            const float nn = tanhf(acc[5][i] + bi5 + rr * (acc[11][i] + bh5));
            const float hv = h[(size_t)m * 32 + 16 + li];
            const float hn = (1.f - zz) * nn + zz * hv;
            out[(size_t)m * 32 + 16 + li] = hn > 0.f ? hn : expm1f(hn);
        }
    }
}

extern "C" void kernel_launch(void* const* d_in, const int* in_sizes, int n_in,
                              void* d_out, int out_size, void* d_ws, size_t ws_size,
                              hipStream_t stream) {
    const float* h   = (const float*)d_in[0];
    const float* Wg  = (const float*)d_in[1];
    const float* al  = (const float*)d_in[2];
    const float* ar  = (const float*)d_in[3];
    const float* Wih = (const float*)d_in[4];
    const float* Whh = (const float*)d_in[5];
    const float* bih = (const float*)d_in[6];
    const float* bhh = (const float*)d_in[7];
    const int* src   = (const int*)d_in[8];
    const int* dst   = (const int*)d_in[9];
    float* out = (float*)d_out;

    // workspace layout (~42 MB)
    float* el = (float*)d_ws;                                 // N*4 f32
    float* er = el + (size_t)N_NODES * 4;                     // N*4 f32
    __hip_bfloat16* featb = (__hip_bfloat16*)(er + (size_t)N_NODES * 4); // N*128 bf16
    __hip_bfloat16* xh    = featb + (size_t)N_NODES * 128;    // 50048*160 bf16
    __hip_bfloat16* hb    = xh + (size_t)50048 * 160;         // N*32 bf16
    __hip_bfloat16* Wc    = hb + (size_t)N_NODES * 32;        // 192*160 bf16
    __hip_bfloat16* Wcomb = Wc + 192 * 160;                   // 144*32 bf16
    int* counts  = (int*)(Wcomb + 144 * 32);                  // N
    int* offsets = counts + N_NODES;                          // N+1
    int* srcs    = offsets + N_NODES + 1;                     // E
    int* rank    = srcs + N_EDGES;                            // E
    int* bsums   = rank + N_EDGES;                            // 49

    hipMemsetAsync(counts, 0, N_NODES * sizeof(int), stream);

    k_prepx<<<(N_NODES * 32 / 4 + 255) / 256, 256, 0, stream>>>(h, hb);
    k_prepw<<<(192 * 160 + 255) / 256, 256, 0, stream>>>(Wih, Whh, Wc);
    k_prepc<<<(144 * 32 + 255) / 256, 256, 0, stream>>>(Wg, al, ar, Wcomb);
    k_hist<<<(N_EDGES + 255) / 256, 256, 0, stream>>>(dst, counts, rank);
    k_feat_mfma<<<(N_NODES / 16 + 3) / 4, 256, 0, stream>>>(hb, Wcomb, featb, el, er);
    const int nscan = (N_NODES + 1023) / 1024;                // 49
    k_scanA<<<nscan, 1024, 0, stream>>>(counts, offsets, bsums);
    k_scanB<<<1, 64, 0, stream>>>(bsums, offsets, nscan);
    k_scanC<<<nscan, 1024, 0, stream>>>(offsets, bsums);
    k_scatter<<<(N_EDGES + 255) / 256, 256, 0, stream>>>(src, dst, offsets, rank, srcs);
    k_aggr<<<(N_NODES + 3) / 4, 256, 0, stream>>>(offsets, srcs, featb, el, er, h, xh);
    k_gru_mfma<<<(N_NODES + 63) / 64, 256, 0, stream>>>(xh, Wc, bih, bhh, h, out);
}

// Round 6
// 192.806 us; speedup vs baseline: 9.7728x; 1.1038x over previous
//
#include <hip/hip_runtime.h>
#include <hip/hip_bf16.h>
#include <cmath>

#define N_NODES 50000
#define N_EDGES 800000

typedef __attribute__((ext_vector_type(8))) short bf16x8;
typedef __attribute__((ext_vector_type(4))) float f32x4;

// ---------------------------------------------------------------------------
// k_prep (fused): [0] h->hb bf16, [1] Wc 192x160 block-diag GRU B,
// [2] Wcomb 144x32 GAT B (feat cols + fused attn dots), [3] zero counts.
// ---------------------------------------------------------------------------
#define PREP_HB   (N_NODES * 32 / 4)          /* 400000 float4 groups */
#define PREP_WC   (192 * 160)
#define PREP_WCB  (144 * 32)
#define PREP_TOT  (PREP_HB + PREP_WC + PREP_WCB + N_NODES)

__global__ __launch_bounds__(256) void k_prep(
        const float* __restrict__ h, const float* __restrict__ Wih,
        const float* __restrict__ Whh, const float* __restrict__ Wg,
        const float* __restrict__ al, const float* __restrict__ ar,
        __hip_bfloat16* __restrict__ hb, __hip_bfloat16* __restrict__ Wc,
        __hip_bfloat16* __restrict__ Wcomb, int* __restrict__ counts) {
    int idx = blockIdx.x * 256 + threadIdx.x;
    if (idx < PREP_HB) {
        const float4 v = ((const float4*)h)[idx];
        __hip_bfloat16* o = hb + (size_t)idx * 4;
        o[0] = __float2bfloat16(v.x);
        o[1] = __float2bfloat16(v.y);
        o[2] = __float2bfloat16(v.z);
        o[3] = __float2bfloat16(v.w);
        return;
    }
    idx -= PREP_HB;
    if (idx < PREP_WC) {
        const int r = idx / 160, k = idx - r * 160;
        float v = 0.f;
        if (r < 96) { if (k < 128) v = Wih[r * 128 + k]; }
        else        { if (k >= 128) v = Whh[(r - 96) * 32 + (k - 128)]; }
        Wc[idx] = __float2bfloat16(v);
        return;
    }
    idx -= PREP_WC;
    if (idx < PREP_WCB) {
        const int row = idx >> 5, k = idx & 31;
        float v = 0.f;
        if (row < 128) {
            v = Wg[k * 128 + row];
        } else if (row < 136) {
            const int hd = (row - 128) & 3;
            const float* a = (row < 132) ? (al + hd * 32) : (ar + hd * 32);
            const float* w = Wg + k * 128 + hd * 32;
#pragma unroll
            for (int f = 0; f < 32; ++f) v = fmaf(w[f], a[f], v);
        }
        Wcomb[idx] = __float2bfloat16(v);
        return;
    }
    idx -= PREP_WCB;
    if (idx < N_NODES) counts[idx] = 0;
}

// ---------------------------------------------------------------------------
// K1: GAT projection via MFMA. M=50000 (3125 16-row tiles), N=144, K=32.
// Tiles 0..7 -> feat (bf16); tile 8 -> el/er f32.
// ---------------------------------------------------------------------------
__global__ __launch_bounds__(256) void k_feat_mfma(
        const __hip_bfloat16* __restrict__ hb, const __hip_bfloat16* __restrict__ Wcomb,
        __hip_bfloat16* __restrict__ feat, float* __restrict__ el, float* __restrict__ er) {
    const int lane = threadIdx.x & 63;
    const int wave = threadIdx.x >> 6;
    const int li = lane & 15, quad = lane >> 4;
    const int mt = blockIdx.x * 4 + wave;
    if (mt >= N_NODES / 16) return;
    const int m_base = mt * 16;
    const bf16x8 a = *(const bf16x8*)(hb + (size_t)(m_base + li) * 32 + quad * 8);
    f32x4 acc[9];
#pragma unroll
    for (int j = 0; j < 9; ++j) acc[j] = (f32x4){0.f, 0.f, 0.f, 0.f};
#pragma unroll
    for (int j = 0; j < 9; ++j) {
        const bf16x8 b = *(const bf16x8*)(Wcomb + (size_t)(j * 16 + li) * 32 + quad * 8);
        acc[j] = __builtin_amdgcn_mfma_f32_16x16x32_bf16(a, b, acc[j], 0, 0, 0);
    }
#pragma unroll
    for (int j = 0; j < 8; ++j) {
#pragma unroll
        for (int i = 0; i < 4; ++i) {
            const int m = m_base + quad * 4 + i;
            feat[(size_t)m * 128 + j * 16 + li] = __float2bfloat16(acc[j][i]);
        }
    }
    if (li < 8) {
#pragma unroll
        for (int i = 0; i < 4; ++i) {
            const int m = m_base + quad * 4 + i;
            if (li < 4) el[m * 4 + li] = acc[8][i];
            else        er[m * 4 + (li - 4)] = acc[8][i];
        }
    }
}

// ---------------------------------------------------------------------------
// K2a: in-degree histogram + per-edge rank within its dst segment
// ---------------------------------------------------------------------------
__global__ __launch_bounds__(256) void k_hist(
        const int* __restrict__ dst, int* __restrict__ counts,
        int* __restrict__ rank) {
    const int e = blockIdx.x * 256 + threadIdx.x;
    if (e < N_EDGES) rank[e] = atomicAdd(&counts[dst[e]], 1);
}

// ---------------------------------------------------------------------------
// K2b: per-1024-chunk exclusive scan + chunk sums
// ---------------------------------------------------------------------------
__global__ __launch_bounds__(1024) void k_scanA(
        const int* __restrict__ counts, int* __restrict__ offsets,
        int* __restrict__ bsums) {
    __shared__ int wtot[16];
    const int t = threadIdx.x;
    const int wave = t >> 6, lane = t & 63;
    const int idx = blockIdx.x * 1024 + t;
    const int v = (idx < N_NODES) ? counts[idx] : 0;
    int x = v;
#pragma unroll
    for (int m = 1; m < 64; m <<= 1) {
        const int y = __shfl_up(x, m, 64);
        if (lane >= m) x += y;
    }
    if (lane == 63) wtot[wave] = x;
    __syncthreads();
    if (t == 0) {
        int s = 0;
#pragma unroll
        for (int i = 0; i < 16; ++i) { const int tmp = wtot[i]; wtot[i] = s; s += tmp; }
        bsums[blockIdx.x] = s;
    }
    __syncthreads();
    if (idx < N_NODES) offsets[idx] = wtot[wave] + x - v;
}

// ---------------------------------------------------------------------------
// K2c: add chunk base (each block computes its own prefix of the 49 bsums
// with one 64-lane shuffle reduction); writes offsets[N]=E.
// ---------------------------------------------------------------------------
__global__ __launch_bounds__(1024) void k_scanC(
        int* __restrict__ offsets, const int* __restrict__ bsums) {
    __shared__ int base_s;
    const int t = threadIdx.x;
    if (t < 64) {
        int v = (t < (int)blockIdx.x) ? bsums[t] : 0;   // blockIdx < 49 <= 64
#pragma unroll
        for (int m = 1; m < 64; m <<= 1) v += __shfl_xor(v, m, 64);
        if (t == 0) base_s = v;
    }
    __syncthreads();
    const int idx = blockIdx.x * 1024 + t;
    if (idx < N_NODES) offsets[idx] += base_s;
    if (blockIdx.x == 0 && t == 0) offsets[N_NODES] = N_EDGES;
}

// ---------------------------------------------------------------------------
// K2d: scatter src ids into dst-sorted order — atomic-free (offsets + rank)
// ---------------------------------------------------------------------------
__global__ __launch_bounds__(256) void k_scatter(
        const int* __restrict__ src, const int* __restrict__ dst,
        const int* __restrict__ offsets, const int* __restrict__ rank,
        int* __restrict__ srcs) {
    const int e = blockIdx.x * 256 + threadIdx.x;
    if (e < N_EDGES) srcs[offsets[dst[e]] + rank[e]] = src[e];
}

// ---------------------------------------------------------------------------
// K3 (fused aggr + GRU): block = 4 waves = 16 nodes = one GRU M-tile.
// Phase 1: wave w aggregates nodes w*4..w*4+3 into LDS xh_tile[16][160]
//          (xh never touches global). Lane owns cols 2l,2l+1 (bf16x2):
//          one wave reads a full 256 B bf16 feat row coalesced.
// Phase 2: GRU GEMM [gi|gh](16,192) = xh_tile(16,160) @ Wc^T, 12 gate-tiles
//          split 3-per-wave; gh-role waves exchange accs via LDS; gi-role
//          waves run the gate epilogue. Frag layouts as verified (§3).
// ---------------------------------------------------------------------------
__global__ __launch_bounds__(256) void k_aggr_gru(
        const int* __restrict__ offsets, const int* __restrict__ srcs,
        const __hip_bfloat16* __restrict__ feat,
        const float* __restrict__ el, const float* __restrict__ er,
        const float* __restrict__ h, const __hip_bfloat16* __restrict__ Wc,
        const float* __restrict__ bih, const float* __restrict__ bhh,
        float* __restrict__ out) {
    __shared__ __hip_bfloat16 xh_tile[16][160];   // 5 KB
    __shared__ int   sl_s[4][64];                 // 1 KB
    __shared__ float eel_s[4][256];               // 4 KB
    __shared__ float ex[2][3][16][16];            // 6 KB gh exchange
    const int wave = threadIdx.x >> 6;
    const int lane = threadIdx.x & 63;
    int*   sl  = sl_s[wave];
    float* eel = eel_s[wave];
    const int hs = lane & 3;          // head for softmax-term lanes
    const int hc = lane >> 4;         // head of this lane's feat columns
    const int mbase = blockIdx.x * 16;

    // ---- phase 1: aggregate 4 nodes per wave ----
    for (int u = 0; u < 4; ++u) {
        const int row = wave * 4 + u;
        const int n = mbase + row;
        const float ern = er[n * 4 + hs];
        const int start = offsets[n], end = offsets[n + 1];
        float ax = 0.f, ay = 0.f, psum = 0.f;
        for (int chunk = start; chunk < end; chunk += 64) {
            const int cnt = min(64, end - chunk);
            if (lane < cnt) sl[lane] = srcs[chunk + lane];
            __builtin_amdgcn_wave_barrier();
#pragma unroll
            for (int p = 0; p < 4; ++p) {
                const int j = p * 64 + lane;       // j&3 == lane&3
                if (j < cnt * 4) {
                    const int s = sl[j >> 2];
                    float v = el[s * 4 + hs] + ern;
                    v = v > 0.f ? v : 0.2f * v;    // leaky_relu(0.2)
                    const float e = expf(v);
                    eel[j] = e;
                    psum += e;
                }
            }
            __builtin_amdgcn_wave_barrier();
            int i = 0;
            for (; i + 4 <= cnt; i += 4) {         // batched for MLP
                const int s0 = sl[i], s1 = sl[i + 1], s2 = sl[i + 2], s3 = sl[i + 3];
                const __hip_bfloat162 f0 = ((const __hip_bfloat162*)(feat + (size_t)s0 * 128))[lane];
                const __hip_bfloat162 f1 = ((const __hip_bfloat162*)(feat + (size_t)s1 * 128))[lane];
                const __hip_bfloat162 f2 = ((const __hip_bfloat162*)(feat + (size_t)s2 * 128))[lane];
                const __hip_bfloat162 f3 = ((const __hip_bfloat162*)(feat + (size_t)s3 * 128))[lane];
                const float w0 = eel[i * 4 + hc];
                const float w1 = eel[(i + 1) * 4 + hc];
                const float w2 = eel[(i + 2) * 4 + hc];
                const float w3 = eel[(i + 3) * 4 + hc];
                ax = fmaf(w0, __bfloat162float(f0.x), ax);
                ay = fmaf(w0, __bfloat162float(f0.y), ay);
                ax = fmaf(w1, __bfloat162float(f1.x), ax);
                ay = fmaf(w1, __bfloat162float(f1.y), ay);
                ax = fmaf(w2, __bfloat162float(f2.x), ax);
                ay = fmaf(w2, __bfloat162float(f2.y), ay);
                ax = fmaf(w3, __bfloat162float(f3.x), ax);
                ay = fmaf(w3, __bfloat162float(f3.y), ay);
            }
            for (; i < cnt; ++i) {
                const int s = sl[i];
                const __hip_bfloat162 f = ((const __hip_bfloat162*)(feat + (size_t)s * 128))[lane];
                const float w = eel[i * 4 + hc];
                ax = fmaf(w, __bfloat162float(f.x), ax);
                ay = fmaf(w, __bfloat162float(f.y), ay);
            }
            __builtin_amdgcn_wave_barrier();
        }
#pragma unroll
        for (int m = 4; m < 64; m <<= 1) psum += __shfl_xor(psum, m, 64);
        const float dn = __shfl(psum, hc, 64);
        const float inv = (end > start) ? 1.f / dn : 0.f;
        __hip_bfloat162 v2;
        v2.x = __float2bfloat16(ax * inv);
        v2.y = __float2bfloat16(ay * inv);
        ((__hip_bfloat162*)&xh_tile[row][0])[lane] = v2;
        if (lane < 32) xh_tile[row][128 + lane] = __float2bfloat16(h[(size_t)n * 32 + lane]);
    }
    __syncthreads();

    // ---- phase 2: GRU MFMA ----
    const int li = lane & 15, quad = lane >> 4;
    const int cb = wave >> 1;          // output col block (0: cols 0-15, 1: 16-31)
    const int ghrole = wave & 1;       // 0: gi tiles, 1: gh tiles
    bf16x8 a[5];
#pragma unroll
    for (int s = 0; s < 5; ++s)
        a[s] = *(const bf16x8*)((const char*)&xh_tile[0][0] + li * 320 + s * 64 + quad * 16);
    f32x4 acc[3];
#pragma unroll
    for (int g = 0; g < 3; ++g) {      // g: 0=r, 1=z, 2=n
        acc[g] = (f32x4){0.f, 0.f, 0.f, 0.f};
        const int j = g * 2 + cb + ghrole * 6;
        const bf16x8* bp = (const bf16x8*)(Wc + (size_t)(j * 16 + li) * 160 + quad * 8);
        acc[g] = __builtin_amdgcn_mfma_f32_16x16x32_bf16(a[0], bp[0],  acc[g], 0, 0, 0);
        acc[g] = __builtin_amdgcn_mfma_f32_16x16x32_bf16(a[1], bp[4],  acc[g], 0, 0, 0);
        acc[g] = __builtin_amdgcn_mfma_f32_16x16x32_bf16(a[2], bp[8],  acc[g], 0, 0, 0);
        acc[g] = __builtin_amdgcn_mfma_f32_16x16x32_bf16(a[3], bp[12], acc[g], 0, 0, 0);
        acc[g] = __builtin_amdgcn_mfma_f32_16x16x32_bf16(a[4], bp[16], acc[g], 0, 0, 0);
    }
    if (ghrole) {
#pragma unroll
        for (int g = 0; g < 3; ++g)
#pragma unroll
            for (int i = 0; i < 4; ++i)
                ex[cb][g][quad * 4 + i][li] = acc[g][i];
    }
    __syncthreads();
    if (!ghrole) {
        const int c = cb * 16 + li;
        const float bir = bih[c],      bhr = bhh[c];
        const float biz = bih[32 + c], bhz = bhh[32 + c];
        const float bin = bih[64 + c], bhn = bhh[64 + c];
#pragma unroll
        for (int i = 0; i < 4; ++i) {
            const int row = quad * 4 + i;
            const int m = mbase + row;
            const float gr = acc[0][i] + bir + ex[cb][0][row][li] + bhr;
            const float gz = acc[1][i] + biz + ex[cb][1][row][li] + bhz;
            const float gnn = acc[2][i] + bin;
            const float ghn = ex[cb][2][row][li] + bhn;
            const float r = 1.f / (1.f + expf(-gr));
            const float z = 1.f / (1.f + expf(-gz));
            const float nn = tanhf(gnn + r * ghn);
            const float hv = h[(size_t)m * 32 + c];
            const float hn = (1.f - z) * nn + z * hv;
            out[(size_t)m * 32 + c] = hn > 0.f ? hn : expm1f(hn);
        }
    }
}

extern "C" void kernel_launch(void* const* d_in, const int* in_sizes, int n_in,
                              void* d_out, int out_size, void* d_ws, size_t ws_size,
                              hipStream_t stream) {
    const float* h   = (const float*)d_in[0];
    const float* Wg  = (const float*)d_in[1];
    const float* al  = (const float*)d_in[2];
    const float* ar  = (const float*)d_in[3];
    const float* Wih = (const float*)d_in[4];
    const float* Whh = (const float*)d_in[5];
    const float* bih = (const float*)d_in[6];
    const float* bhh = (const float*)d_in[7];
    const int* src   = (const int*)d_in[8];
    const int* dst   = (const int*)d_in[9];
    float* out = (float*)d_out;

    // workspace layout (~27 MB)
    float* el = (float*)d_ws;                                 // N*4 f32
    float* er = el + (size_t)N_NODES * 4;                     // N*4 f32
    __hip_bfloat16* featb = (__hip_bfloat16*)(er + (size_t)N_NODES * 4); // N*128 bf16
    __hip_bfloat16* hb    = featb + (size_t)N_NODES * 128;    // N*32 bf16
    __hip_bfloat16* Wc    = hb + (size_t)N_NODES * 32;        // 192*160 bf16
    __hip_bfloat16* Wcomb = Wc + 192 * 160;                   // 144*32 bf16
    int* counts  = (int*)(Wcomb + 144 * 32);                  // N
    int* offsets = counts + N_NODES;                          // N+1
    int* srcs    = offsets + N_NODES + 1;                     // E
    int* rank    = srcs + N_EDGES;                            // E
    int* bsums   = rank + N_EDGES;                            // 49

    k_prep<<<(PREP_TOT + 255) / 256, 256, 0, stream>>>(
        h, Wih, Whh, Wg, al, ar, hb, Wc, Wcomb, counts);
    k_feat_mfma<<<(N_NODES / 16 + 3) / 4, 256, 0, stream>>>(hb, Wcomb, featb, el, er);
    k_hist<<<(N_EDGES + 255) / 256, 256, 0, stream>>>(dst, counts, rank);
    const int nscan = (N_NODES + 1023) / 1024;                // 49
    k_scanA<<<nscan, 1024, 0, stream>>>(counts, offsets, bsums);
    k_scanC<<<nscan, 1024, 0, stream>>>(offsets, bsums);
    k_scatter<<<(N_EDGES + 255) / 256, 256, 0, stream>>>(src, dst, offsets, rank, srcs);
    k_aggr_gru<<<N_NODES / 16, 256, 0, stream>>>(
        offsets, srcs, featb, el, er, h, Wc, bih, bhh, out);
}